// Round 2
// baseline (156.495 us; speedup 1.0000x reference)
//
#include <hip/hip_runtime.h>
#include <math.h>

#define W 131072
#define FR 63     // floats per pose3d frame (3*21)
#define NB 20
#define WPB 16              // waves (frames) per block
#define BLK (WPB * 64)      // 1024 threads
#define NBLOCKS (W / WPB)   // 8192

// One wave per loss index w (0..W-1). Lane l (<63) holds pose element
// coord*21+joint = l of the frames it loads. Dynamic joint gathers are
// ds_bpermute shuffles instead of LDS reads.
__global__ __launch_bounds__(BLK) void loss_pass1(
    const float* __restrict__ pose3d,
    const float* __restrict__ cam,
    const float* __restrict__ p2d,
    const float* __restrict__ blen,
    const float* __restrict__ ldir,
    const int* __restrict__ bcon,
    const int* __restrict__ lcon,
    float* __restrict__ partial)
{
  __shared__ float sWave[WPB];
  const int tid  = threadIdx.x;
  const int lane = tid & 63;
  const int wv   = tid >> 6;
  const int w    = blockIdx.x * WPB + wv;                 // 0..W-1
  const int wu   = __builtin_amdgcn_readfirstlane(w);     // wave-uniform SGPR

  // ---- pose loads: frames w (P0), w+1 (P1), w+2 (P2), one element/lane ----
  float P0 = 0.0f, P1 = 0.0f, P2 = 0.0f;
  if (lane < FR) {
    P0 = pose3d[(size_t)wu * FR + lane];
    P1 = pose3d[(size_t)(wu + 1) * FR + lane];
    if (wu < W - 1) P2 = pose3d[(size_t)(wu + 2) * FR + lane];
  }

  // ---- smoothness: (P2 - 2*P1 + P0)^2, valid for w <= W-2 ----
  float d2 = P2 - 2.0f * P1 + P0;
  float acc_smooth = (wu < W - 1) ? d2 * d2 : 0.0f;   // lane>=63 contributes 0

  // ---- projection: lanes 0..41 = (i,k), i = lane/21, k = lane%21 ----
  float acc_proj = 0.0f;
  {
    int k = lane % 21;
    float pk0 = __shfl(P1, k, 64);
    float pk1 = __shfl(P1, k + 21, 64);
    float pk2 = __shfl(P1, k + 42, 64);
    const float* cp = cam + (size_t)wu * 6;   // uniform address -> s_load
    float c0 = cp[0], c1 = cp[1], c2 = cp[2], c3 = cp[3], c4 = cp[4], c5 = cp[5];
    bool row1 = (lane >= 21);
    float pr = row1 ? (c3 * pk0 + c4 * pk1 + c5 * pk2)
                    : (c0 * pk0 + c1 * pk1 + c2 * pk2);
    if (lane < 42) {
      float t = p2d[(size_t)wu * 42 + lane];
      float d = pr - t;
      acc_proj = d * d;
    }
  }

  // ---- (c,b) mapping for bone/lift: b = lane%20, c = lane/20 (clamped) ----
  int b = lane % 20;
  int c = lane / 20; if (c > 2) c = 2;
  const int2* bc2 = (const int2*)bcon;
  const int2* lc2 = (const int2*)lcon;
  int2 bcp = bc2[b];
  int2 lcp = lc2[b];
  float bl = blen[b];

  // ---- bone length loss: frame w+1 for every wave; wave 0 adds frame 0 ----
  float acc_bone = 0.0f;
  {
    int ic = c * 21 + bcp.x, ip = c * 21 + bcp.y;
    float bx = __shfl(P1, ic, 64) - __shfl(P1, ip, 64);
    float sq = bx * bx;
    float L  = __shfl(sq, b, 64) + __shfl(sq, b + 20, 64) + __shfl(sq, b + 40, 64);
    if (lane < 20) { float t = L - bl; acc_bone = t * t; }
    if (wu == 0) {  // uniform branch: all lanes enter together
      float bx0 = __shfl(P0, ic, 64) - __shfl(P0, ip, 64);
      float sq0 = bx0 * bx0;
      float L0  = __shfl(sq0, b, 64) + __shfl(sq0, b + 20, 64) + __shfl(sq0, b + 40, 64);
      if (lane < 20) { float t = L0 - bl; acc_bone += t * t; }
    }
  }

  // ---- lift direction loss: lanes 0..59, layout matches ldir flat w*60+l ----
  float acc_lift = 0.0f;
  {
    int ic = c * 21 + lcp.x, ip = c * 21 + lcp.y;
    float lx  = __shfl(P1, ic, 64) - __shfl(P1, ip, 64);
    float lsq = lx * lx;
    float LL  = __shfl(lsq, b, 64) + __shfl(lsq, b + 20, 64) + __shfl(lsq, b + 40, 64);
    if (lane < 60) {
      float inv = rsqrtf(LL);
      float est = lx * inv;
      float ld  = ldir[(size_t)wu * 60 + lane];
      float d   = ld - est;
      acc_lift = d * d;
    }
  }

  // ---- weighted combine + wave/block reduction ----
  float total = acc_proj * (1.0f / 42.0f) + acc_bone * (1.0f / 20.0f)
              + acc_smooth * (0.5f / 63.0f) + acc_lift * (0.1f / 63.0f);
#pragma unroll
  for (int off = 32; off > 0; off >>= 1) total += __shfl_xor(total, off, 64);
  if (lane == 0) sWave[wv] = total;
  __syncthreads();
  if (tid == 0) {
    float s = 0.0f;
#pragma unroll
    for (int i = 0; i < WPB; ++i) s += sWave[i];
    partial[blockIdx.x] = s;
  }
}

__global__ __launch_bounds__(1024) void loss_pass2(
    const float* __restrict__ partial, float* __restrict__ out)
{
  __shared__ float sW[16];
  int tid = threadIdx.x;
  float s = 0.0f;
  for (int i = tid; i < NBLOCKS; i += 1024) s += partial[i];
#pragma unroll
  for (int off = 32; off > 0; off >>= 1) s += __shfl_xor(s, off, 64);
  if ((tid & 63) == 0) sW[tid >> 6] = s;
  __syncthreads();
  if (tid == 0) {
    float t = 0.0f;
#pragma unroll
    for (int i = 0; i < 16; ++i) t += sW[i];
    out[0] = t;
  }
}

extern "C" void kernel_launch(void* const* d_in, const int* in_sizes, int n_in,
                              void* d_out, int out_size, void* d_ws, size_t ws_size,
                              hipStream_t stream) {
  const float* pose3d = (const float*)d_in[0];
  const float* cam    = (const float*)d_in[1];
  const float* p2d    = (const float*)d_in[2];
  const float* blen   = (const float*)d_in[3];
  const float* ldir   = (const float*)d_in[4];
  const int*   bcon   = (const int*)d_in[5];
  const int*   lcon   = (const int*)d_in[6];
  float* out     = (float*)d_out;
  float* partial = (float*)d_ws;   // 8192 floats = 32 KB

  loss_pass1<<<NBLOCKS, BLK, 0, stream>>>(pose3d, cam, p2d, blen, ldir,
                                          bcon, lcon, partial);
  loss_pass2<<<1, 1024, 0, stream>>>(partial, out);
}

// Round 3
// 138.344 us; speedup vs baseline: 1.1312x; 1.1312x over previous
//
#include <hip/hip_runtime.h>
#include <math.h>

#define W 131072
#define FR 63                 // floats per pose3d frame (3*21)
#define NB 20
#define BLKT 64               // threads per block = frames per block (1 wave)
#define TFR (BLKT + 2)        // 66 frames staged
#define PITCH 67              // LDS floats per frame; odd -> conflict-free lane stride
#define NBLOCKS (W / BLKT)    // 2048, exact

__global__ __launch_bounds__(BLKT) void loss_pass1(
    const float* __restrict__ pose3d,
    const float* __restrict__ cam,
    const float* __restrict__ p2d,
    const float* __restrict__ blen,
    const float* __restrict__ ldir,
    const int* __restrict__ bcon,
    const int* __restrict__ lcon,
    float* __restrict__ partial)
{
  __shared__ float sP[TFR * PITCH];   // 66*67*4 = 17688 B
  const int tid = threadIdx.x;
  const int blk = blockIdx.x;
  const int f0 = blk * BLKT;
  const int w  = f0 + tid;            // 0..W-1 always (W % 64 == 0)

  // ---- stage pose3d frames [f0, f0+66) into LDS with pitch remap ----
  {
    const float* src = pose3d + (size_t)f0 * FR;
    const int avail = (W + 1) * FR - f0 * FR;
    const int lim = (TFR * FR < avail) ? TFR * FR : avail;   // floats present
    const int n4 = (TFR * FR + 3) / 4;                        // 1040 float4 slots
    for (int q = tid; q < n4; q += BLKT) {
      int j = 4 * q;
      int f = j / FR, e = j - f * FR;
      if (j + 3 < lim) {
        float4 v = *(const float4*)(src + j);
        float vv[4] = {v.x, v.y, v.z, v.w};
#pragma unroll
        for (int k = 0; k < 4; ++k) {
          sP[f * PITCH + e] = vv[k];
          if (++e == FR) { e = 0; ++f; }
        }
      } else {
#pragma unroll
        for (int k = 0; k < 4; ++k) {
          if (j + k < lim) sP[f * PITCH + e] = src[j + k];
          if (++e == FR) { e = 0; ++f; }
        }
      }
    }
  }
  __syncthreads();

  const float* P0 = sP + tid * PITCH;   // frame w
  const float* P1 = P0 + PITCH;         // frame w+1
  const float* P2 = P1 + PITCH;         // frame w+2

  // frame w+1 into registers (static-index uses: smooth + proj)
  float p1[FR];
#pragma unroll
  for (int e = 0; e < FR; ++e) p1[e] = P1[e];

  // ---- smoothness (second difference), valid for w <= W-2 ----
  float acc_smooth = 0.0f;
  if (w < W - 1) {
#pragma unroll
    for (int e = 0; e < FR; ++e) {
      float d2 = P2[e] - 2.0f * p1[e] + P0[e];
      acc_smooth += d2 * d2;
    }
  }

  // ---- projection loss (frame w+1) ----
  float acc_proj = 0.0f;
  {
    const float2* camv = (const float2*)(cam + (size_t)w * 6);
    float2 c0 = camv[0], c1 = camv[1], c2 = camv[2];
    float cr[2][3] = {{c0.x, c0.y, c1.x}, {c1.y, c2.x, c2.y}};
    const float2* pv = (const float2*)(p2d + (size_t)w * 42);
#pragma unroll
    for (int k = 0; k < 21; ++k) {
      float2 v = pv[k];
      {
        const int idx = 2 * k, i = idx / 21, j = idx % 21;
        float pr = cr[i][0] * p1[j] + cr[i][1] * p1[21 + j] + cr[i][2] * p1[42 + j];
        float d = pr - v.x;
        acc_proj += d * d;
      }
      {
        const int idx = 2 * k + 1, i = idx / 21, j = idx % 21;
        float pr = cr[i][0] * p1[j] + cr[i][1] * p1[21 + j] + cr[i][2] * p1[42 + j];
        float d = pr - v.y;
        acc_proj += d * d;
      }
    }
  }

  // ---- lift (frame w+1) + bone (frame w+1, covering frames 1..W) ----
  float acc_bone = 0.0f, acc_lift = 0.0f;
  {
    const int2* bc2 = (const int2*)bcon;
    const int2* lc2 = (const int2*)lcon;
    const float4* lv = (const float4*)(ldir + (size_t)w * 60);
    float ld[60];
#pragma unroll
    for (int k = 0; k < 15; ++k) {
      float4 v = lv[k];
      ld[4 * k] = v.x; ld[4 * k + 1] = v.y; ld[4 * k + 2] = v.z; ld[4 * k + 3] = v.w;
    }
#pragma unroll
    for (int b = 0; b < NB; ++b) {
      int2 lc = lc2[b];
      float dx = P1[lc.x]      - P1[lc.y];
      float dy = P1[21 + lc.x] - P1[21 + lc.y];
      float dz = P1[42 + lc.x] - P1[42 + lc.y];
      float S  = dx * dx + dy * dy + dz * dz;
      float inv = rsqrtf(S);
      float ex = ld[b]      - dx * inv;
      float ey = ld[20 + b] - dy * inv;
      float ez = ld[40 + b] - dz * inv;
      acc_lift += ex * ex + ey * ey + ez * ez;

      int2 bc = bc2[b];
      float Sb;
      if (bc.x == lc.x && bc.y == lc.y) {   // wave-uniform (scalar) branch
        Sb = S;
      } else {
        float bx = P1[bc.x]      - P1[bc.y];
        float by = P1[21 + bc.x] - P1[21 + bc.y];
        float bz = P1[42 + bc.x] - P1[42 + bc.y];
        Sb = bx * bx + by * by + bz * bz;
      }
      float t = Sb - blen[b];
      acc_bone += t * t;
    }
    // frame 0's bone term (only thread with w == 0)
    if (w == 0) {
#pragma unroll
      for (int b = 0; b < NB; ++b) {
        int2 bc = bc2[b];
        float bx = P0[bc.x]      - P0[bc.y];
        float by = P0[21 + bc.x] - P0[21 + bc.y];
        float bz = P0[42 + bc.x] - P0[42 + bc.y];
        float Sb = bx * bx + by * by + bz * bz;
        float t = Sb - blen[b];
        acc_bone += t * t;
      }
    }
  }

  // ---- weighted combine + single-wave reduction ----
  float s = acc_proj * (1.0f / 42.0f) + acc_bone * (1.0f / 20.0f)
          + acc_smooth * (0.5f / 63.0f) + acc_lift * (0.1f / 63.0f);
#pragma unroll
  for (int off = 32; off > 0; off >>= 1) s += __shfl_xor(s, off, 64);
  if (tid == 0) partial[blk] = s;
}

__global__ __launch_bounds__(256) void loss_pass2(
    const float* __restrict__ partial, float* __restrict__ out)
{
  __shared__ float sW[4];
  int tid = threadIdx.x;
  float s = 0.0f;
#pragma unroll
  for (int i = 0; i < NBLOCKS / 256; ++i) s += partial[i * 256 + tid];
#pragma unroll
  for (int off = 32; off > 0; off >>= 1) s += __shfl_xor(s, off, 64);
  if ((tid & 63) == 0) sW[tid >> 6] = s;
  __syncthreads();
  if (tid == 0) {
    float t = 0.0f;
#pragma unroll
    for (int i = 0; i < 4; ++i) t += sW[i];
    out[0] = t;
  }
}

extern "C" void kernel_launch(void* const* d_in, const int* in_sizes, int n_in,
                              void* d_out, int out_size, void* d_ws, size_t ws_size,
                              hipStream_t stream) {
  const float* pose3d = (const float*)d_in[0];
  const float* cam    = (const float*)d_in[1];
  const float* p2d    = (const float*)d_in[2];
  const float* blen   = (const float*)d_in[3];
  const float* ldir   = (const float*)d_in[4];
  const int*   bcon   = (const int*)d_in[5];
  const int*   lcon   = (const int*)d_in[6];
  float* out     = (float*)d_out;
  float* partial = (float*)d_ws;   // 2048 floats = 8 KB

  loss_pass1<<<NBLOCKS, BLKT, 0, stream>>>(pose3d, cam, p2d, blen, ldir,
                                           bcon, lcon, partial);
  loss_pass2<<<1, 256, 0, stream>>>(partial, out);
}

// Round 4
// 126.115 us; speedup vs baseline: 1.2409x; 1.0970x over previous
//
#include <hip/hip_runtime.h>
#include <math.h>

#define W 131072
#define FR 63                 // floats per pose3d frame (3*21)
#define NB 20
#define FPB 32                // frames per block
#define BLKT 128              // 4 threads per frame, 2 waves
#define TFR (FPB + 2)         // 34 frames staged
#define SP_PAD 2144           // 34*63=2142, padded to multiple of 4
#define NBLOCKS (W / FPB)     // 4096

__global__ __launch_bounds__(BLKT) void loss_pass1(
    const float* __restrict__ pose3d,
    const float* __restrict__ cam,
    const float* __restrict__ p2d,
    const float* __restrict__ blen,
    const float* __restrict__ ldir,
    const int* __restrict__ bcon,
    const int* __restrict__ lcon,
    float* __restrict__ partial)
{
  __shared__ float sP[SP_PAD];   // 8576 B
  __shared__ float sWave[2];

  const int tid = threadIdx.x;
  const int blk = blockIdx.x;
  const int f0 = blk * FPB;
  const int s  = tid & 3;        // sub-thread within frame
  const int fl = tid >> 2;       // local frame 0..31
  const int w  = f0 + fl;        // 0..W-1 (exact)

  // ---- stage frames [f0, f0+34) into LDS, aligned float4 -> b128 ----
  {
    const float* src = pose3d + (size_t)f0 * FR;
    const int avail = ((W + 1) - f0) * FR;   // floats present from src
#pragma unroll
    for (int it = 0; it < 5; ++it) {
      int q = tid + it * BLKT;
      if (q < SP_PAD / 4) {
        int j = 4 * q;
        if (j + 4 <= avail) {
          *(float4*)(sP + j) = *(const float4*)(src + j);
        } else {
#pragma unroll
          for (int k = 0; k < 4; ++k)
            sP[j + k] = (j + k < avail) ? src[j + k] : 0.0f;
        }
      }
    }
  }
  __syncthreads();

  const float* P0 = sP + fl * FR;   // frame w
  const float* P1 = P0 + FR;        // frame w+1
  const float* P2 = P1 + FR;        // frame w+2

  // ---- smoothness: elements [16s, 16s+16) of the second difference ----
  float acc_smooth = 0.0f;
  if (w < W - 1) {
#pragma unroll
    for (int k = 0; k < 16; ++k) {
      int e = 16 * s + k;
      if (e < FR) {
        float d2 = P2[e] - 2.0f * P1[e] + P0[e];
        acc_smooth += d2 * d2;
      }
    }
  }

  // ---- projection: joints j = s, s+4, ... ----
  float acc_proj = 0.0f;
  {
    const float2* cp = (const float2*)(cam + (size_t)w * 6);  // 8B aligned (24w)
    float2 ca = cp[0], cb = cp[1], cc = cp[2];
    const float* pr = p2d + (size_t)w * 42;
#pragma unroll
    for (int k = 0; k < 6; ++k) {
      int j = s + 4 * k;
      if (j < 21) {
        float x = P1[j], y = P1[21 + j], z = P1[42 + j];
        float p0 = ca.x * x + ca.y * y + cb.x * z;
        float p1v = cb.y * x + cc.x * y + cc.y * z;
        float d0 = p0 - pr[j];
        float d1 = p1v - pr[21 + j];
        acc_proj += d0 * d0 + d1 * d1;
      }
    }
  }

  // ---- lift + bone: bones b = s, s+4, ... (frame w+1; covers bones 1..W) ----
  float acc_bone = 0.0f, acc_lift = 0.0f;
  {
    const int2* bc2 = (const int2*)bcon;
    const int2* lc2 = (const int2*)lcon;
    const float* lr = ldir + (size_t)w * 60;
#pragma unroll
    for (int k = 0; k < 5; ++k) {
      int b = s + 4 * k;
      int2 lc = lc2[b];
      float dx = P1[lc.x]      - P1[lc.y];
      float dy = P1[21 + lc.x] - P1[21 + lc.y];
      float dz = P1[42 + lc.x] - P1[42 + lc.y];
      float S = dx * dx + dy * dy + dz * dz;
      float inv = rsqrtf(S);
      float ex = lr[b]      - dx * inv;
      float ey = lr[20 + b] - dy * inv;
      float ez = lr[40 + b] - dz * inv;
      acc_lift += ex * ex + ey * ey + ez * ez;

      int2 bc = bc2[b];
      float Sb = S;
      if (bc.x != lc.x || bc.y != lc.y) {   // dataset: never taken (execz skip)
        float bx = P1[bc.x]      - P1[bc.y];
        float by = P1[21 + bc.x] - P1[21 + bc.y];
        float bz = P1[42 + bc.x] - P1[42 + bc.y];
        Sb = bx * bx + by * by + bz * bz;
      }
      float t = Sb - blen[b];
      acc_bone += t * t;
    }
    if (w == 0) {   // frame 0's bone term
#pragma unroll
      for (int k = 0; k < 5; ++k) {
        int b = s + 4 * k;
        int2 bc = bc2[b];
        float bx = P0[bc.x]      - P0[bc.y];
        float by = P0[21 + bc.x] - P0[21 + bc.y];
        float bz = P0[42 + bc.x] - P0[42 + bc.y];
        float Sb = bx * bx + by * by + bz * bz;
        float t = Sb - blen[b];
        acc_bone += t * t;
      }
    }
  }

  // ---- weighted combine + block reduction (2 waves) ----
  float tot = acc_proj * (1.0f / 42.0f) + acc_bone * (1.0f / 20.0f)
            + acc_smooth * (0.5f / 63.0f) + acc_lift * (0.1f / 63.0f);
#pragma unroll
  for (int off = 32; off > 0; off >>= 1) tot += __shfl_xor(tot, off, 64);
  if ((tid & 63) == 0) sWave[tid >> 6] = tot;
  __syncthreads();
  if (tid == 0) partial[blk] = sWave[0] + sWave[1];
}

__global__ __launch_bounds__(256) void loss_pass2(
    const float* __restrict__ partial, float* __restrict__ out)
{
  __shared__ float sW[4];
  int tid = threadIdx.x;
  float s = 0.0f;
#pragma unroll
  for (int i = 0; i < NBLOCKS / 256; ++i) s += partial[i * 256 + tid];
#pragma unroll
  for (int off = 32; off > 0; off >>= 1) s += __shfl_xor(s, off, 64);
  if ((tid & 63) == 0) sW[tid >> 6] = s;
  __syncthreads();
  if (tid == 0) {
    float t = 0.0f;
#pragma unroll
    for (int i = 0; i < 4; ++i) t += sW[i];
    out[0] = t;
  }
}

extern "C" void kernel_launch(void* const* d_in, const int* in_sizes, int n_in,
                              void* d_out, int out_size, void* d_ws, size_t ws_size,
                              hipStream_t stream) {
  const float* pose3d = (const float*)d_in[0];
  const float* cam    = (const float*)d_in[1];
  const float* p2d    = (const float*)d_in[2];
  const float* blen   = (const float*)d_in[3];
  const float* ldir   = (const float*)d_in[4];
  const int*   bcon   = (const int*)d_in[5];
  const int*   lcon   = (const int*)d_in[6];
  float* out     = (float*)d_out;
  float* partial = (float*)d_ws;   // 4096 floats = 16 KB

  loss_pass1<<<NBLOCKS, BLKT, 0, stream>>>(pose3d, cam, p2d, blen, ldir,
                                           bcon, lcon, partial);
  loss_pass2<<<1, 256, 0, stream>>>(partial, out);
}